// Round 1
// 715.716 us; speedup vs baseline: 1.1149x; 1.1149x over previous
//
#include <hip/hip_runtime.h>
#include <hip/hip_bf16.h>
#include <stdint.h>

#define N_NODES 4096
#define N_EDGES 8192
#define IN_V    512
#define OUT_V   512
#define IN_E    128

typedef __bf16 bf16;
typedef __bf16 bf16x8 __attribute__((ext_vector_type(8)));
typedef __bf16 bf16x4 __attribute__((ext_vector_type(4)));
typedef float  f32x4  __attribute__((ext_vector_type(4)));

// Async global->LDS, 16B per lane. LDS dest is wave-uniform base + lane*16.
__device__ __forceinline__ void g2l16(const void* g, void* l) {
    __builtin_amdgcn_global_load_lds(
        (const __attribute__((address_space(1))) void*)g,
        (__attribute__((address_space(3))) void*)l,
        16, 0, 0);
}

// -------- e_scale = H_e @ p^T : one wave per edge row (K=128) --------
__global__ void escale_k(const float* __restrict__ He, const float* __restrict__ p,
                         float* __restrict__ es) {
    const int row  = blockIdx.x * 4 + (threadIdx.x >> 6);
    const int lane = threadIdx.x & 63;
    const float* r = He + (size_t)row * IN_E;
    float v = r[lane] * p[lane] + r[lane + 64] * p[lane + 64];
#pragma unroll
    for (int off = 32; off > 0; off >>= 1) v += __shfl_down(v, off);
    if (lane == 0) es[row] = v;
}

// -------- T (f32 [N][E]) -> Tb = bf16(T), Ts = bf16(T * e_scale[col]) --------
__global__ void conv_T(const float* __restrict__ T, const float* __restrict__ es,
                       bf16* __restrict__ Ts, bf16* __restrict__ Tb) {
    const size_t i4 = (size_t)blockIdx.x * 256 + threadIdx.x;  // float4 index
    const f32x4 t = ((const f32x4*)T)[i4];
    const int  c4 = (int)(i4 & (N_EDGES / 4 - 1));
    const f32x4 s = ((const f32x4*)es)[c4];
    bf16x4 tb, ts;
#pragma unroll
    for (int j = 0; j < 4; j++) { tb[j] = (bf16)t[j]; ts[j] = (bf16)(t[j] * s[j]); }
    ((bf16x4*)Tb)[i4] = tb;
    ((bf16x4*)Ts)[i4] = ts;
}

// -------- generic f32 -> bf16 (vectorized x4) --------
__global__ void conv_bf16(const float* __restrict__ in, bf16* __restrict__ o) {
    const size_t i4 = (size_t)blockIdx.x * 256 + threadIdx.x;
    const f32x4 t = ((const f32x4*)in)[i4];
    bf16x4 v;
#pragma unroll
    for (int j = 0; j < 4; j++) v[j] = (bf16)t[j];
    ((bf16x4*)o)[i4] = v;
}

// -------- weight [512][512] f32 -> Wt bf16 with Wt[j][k] = W[k][j] --------
__global__ void transW(const float* __restrict__ W, bf16* __restrict__ Wt) {
    const int idx = blockIdx.x * 256 + threadIdx.x;  // output index j*512+k
    const int j = idx >> 9, k = idx & 511;
    Wt[idx] = (bf16)W[k * OUT_V + j];
}

// -------- finalize: out[i][j] = bias[j] + 0.5 * sum_z partial[z][i][j] -------
// Replaces the old atomicAdd split-K epilogue (8.4M global f32 RMWs).
__global__ void finalize_k(const float* __restrict__ part, const float* __restrict__ bias,
                           float* __restrict__ out) {
    const size_t i4  = (size_t)blockIdx.x * 256 + threadIdx.x;
    const size_t npp = (size_t)N_NODES * OUT_V / 4;  // one partial in f32x4 units
    const f32x4 b  = ((const f32x4*)bias)[i4 & (OUT_V / 4 - 1)];
    const f32x4 s0 = ((const f32x4*)part)[i4];
    const f32x4 s1 = ((const f32x4*)part)[i4 + npp];
    const f32x4 s2 = ((const f32x4*)part)[i4 + 2 * npp];
    const f32x4 s3 = ((const f32x4*)part)[i4 + 3 * npp];
    f32x4 r;
#pragma unroll
    for (int j = 0; j < 4; j++) r[j] = b[j] + 0.5f * ((s0[j] + s1[j]) + (s2[j] + s3[j]));
    ((f32x4*)out)[i4] = r;
}

// -------- BT-GEMM: C[i][j] = sum_k A[i,k]*B[j,k]  (A: M x K, B: N x K, bf16)
// 128x128 block tile, BK=32, 256 threads (4 waves in 2x2, 64x64 each),
// 16x16x32 bf16 MFMA, global_load_lds width-16 staging.
// NEW this round: 2-phase double-buffered prefetch (stage tile t+1 before
// computing tile t; single vmcnt-drain barrier per tile — T3-minimum recipe).
// K = row stride (full reduction dim); KS = this block's K-slice length,
// slice index = blockIdx.z (split-K; KS==K, gridDim.z=1 for no split).
// EPI 0: store bf16 C                                (out = bf16[M][N])
// EPI 1: SYMMETRIC A2 epilogue (M1 = M1^T): 1D triangular grid with
//        XCD-chunked swizzle (528 = 8*66), block (bx,by), by<=bx writes
//        (C+1)*adj at (i,j) AND (j,i); diag elems -> 2*adj.
// EPI 3: store f32 C into partial[blockIdx.z] (split-K, no atomics)
template <int EPI>
__global__ __launch_bounds__(256, 3) void gemm_bt(
    const bf16* __restrict__ A, const bf16* __restrict__ B,
    const float* __restrict__ aux, void* __restrict__ out,
    int M, int N, int K, int KS) {
    __shared__ __align__(16) bf16 As[2][128 * 32];
    __shared__ __align__(16) bf16 Bs[2][128 * 32];
    const int tid  = threadIdx.x;
    const int wave = tid >> 6;
    const int lane = tid & 63;

    int bx, by;
    if constexpr (EPI == 1) {
        // XCD-chunked swizzle: 528 blocks = 8 XCDs x 66 contiguous triangular
        // indices -> each XCD's L2 keeps ~2 bx-rows' A-slabs resident.
        int idx = (int)blockIdx.x;
        idx = (idx & 7) * 66 + (idx >> 3);
        // triangular decode: idx -> (bx, by), by <= bx
        bx = (int)((sqrtf(8.0f * (float)idx + 1.0f) - 1.0f) * 0.5f);
        while ((bx + 1) * (bx + 2) / 2 <= idx) bx++;
        while (bx * (bx + 1) / 2 > idx) bx--;
        by = idx - bx * (bx + 1) / 2;
    } else {
        bx = blockIdx.x;
        by = blockIdx.y;
    }
    const int bm0 = bx * 128;
    const int bn0 = by * 128;
    const int wr  = (wave >> 1) * 64;  // wave row offset in tile
    const int wc  = (wave & 1) * 64;   // wave col offset in tile

    // staging: tile is packed [128 rows][32 bf16] = 64B/row; each wave covers
    // 1KB per issue (16 rows), 2 issues per operand.
    const int sr = wave * 16 + (lane >> 2);   // tile row, issue 0
    const int sb = (lane & 3) * 16;           // byte offset within 64B row
    const char* Ab0 = (const char*)A + (size_t)(bm0 + sr) * K * 2 + sb;
    const char* Ab1 = (const char*)A + (size_t)(bm0 + sr + 64) * K * 2 + sb;
    const char* Bb0 = (const char*)B + (size_t)(bn0 + sr) * K * 2 + sb;
    const char* Bb1 = (const char*)B + (size_t)(bn0 + sr + 64) * K * 2 + sb;
    const int woff = wave * 1024;

    f32x4 acc[4][4];
#pragma unroll
    for (int i = 0; i < 4; i++)
#pragma unroll
        for (int j = 0; j < 4; j++) acc[i][j] = f32x4{0.f, 0.f, 0.f, 0.f};

    // LDS read offsets (elements): A frag lane m=lane&15, k=(lane>>4)*8
    const int a_off = (wr + (lane & 15)) * 32 + (lane >> 4) * 8;
    const int b_off = (wc + (lane & 15)) * 32 + (lane >> 4) * 8;

    auto do_stage = [&](bf16* AsB, bf16* BsB, size_t kb) {
        g2l16(Ab0 + kb, (char*)AsB + woff);
        g2l16(Ab1 + kb, (char*)AsB + woff + 4096);
        g2l16(Bb0 + kb, (char*)BsB + woff);
        g2l16(Bb1 + kb, (char*)BsB + woff + 4096);
    };
    auto do_mfma = [&](const bf16* AsB, const bf16* BsB) {
        bf16x8 a[4], b[4];
#pragma unroll
        for (int mt = 0; mt < 4; mt++) a[mt] = *(const bf16x8*)(AsB + a_off + mt * 512);
#pragma unroll
        for (int nt = 0; nt < 4; nt++) b[nt] = *(const bf16x8*)(BsB + b_off + nt * 512);
#pragma unroll
        for (int mt = 0; mt < 4; mt++)
#pragma unroll
            for (int nt = 0; nt < 4; nt++)
                acc[mt][nt] = __builtin_amdgcn_mfma_f32_16x16x32_bf16(
                    a[mt], b[nt], acc[mt][nt], 0, 0, 0);
    };

    const int k_beg = (int)blockIdx.z * KS;
    const int k_end = k_beg + KS;
    // 2-phase pipeline, unrolled x2 so buffer indices are compile-time
    // (runtime-indexed LDS pointers would defeat the scheduler).
    do_stage(As[0], Bs[0], (size_t)k_beg * 2);
    __syncthreads();
    for (int k0 = k_beg; k0 < k_end; k0 += 64) {
        if (k0 + 32 < k_end) do_stage(As[1], Bs[1], (size_t)(k0 + 32) * 2);
        do_mfma(As[0], Bs[0]);
        __syncthreads();  // drains this iter's prefetch too (2-phase cost)
        if (k0 + 64 < k_end) do_stage(As[0], Bs[0], (size_t)(k0 + 64) * 2);
        do_mfma(As[1], Bs[1]);
        __syncthreads();
    }

    // Epilogue. C/D layout: col = lane&15, row = (lane>>4)*4 + reg  [m89/m91]
    const int col = lane & 15;
    const int r0  = (lane >> 4) * 4;
    float* po = nullptr;
    if constexpr (EPI == 3)
        po = (float*)out + (size_t)blockIdx.z * ((size_t)M * (size_t)N);
#pragma unroll
    for (int mt = 0; mt < 4; mt++) {
#pragma unroll
        for (int nt = 0; nt < 4; nt++) {
            const int gn = bn0 + wc + nt * 16 + col;
#pragma unroll
            for (int r = 0; r < 4; r++) {
                const int gm = bm0 + wr + mt * 16 + r0 + r;
                const float c = acc[mt][nt][r];
                if constexpr (EPI == 0) {
                    ((bf16*)out)[(size_t)gm * N + gn] = (bf16)c;
                } else if constexpr (EPI == 1) {
                    const float av = aux[(size_t)gm * N + gn];
                    const float v  = (gm == gn) ? 2.0f * av : (c + 1.0f) * av;
                    ((bf16*)out)[(size_t)gm * N + gn] = (bf16)v;
                } else {
                    po[(size_t)gm * N + gn] = c;
                }
            }
            if constexpr (EPI == 1) {
                // mirror write: A2[gn][gm..gm+3] (contiguous, vectorized).
                // Skip on diagonal blocks (normal path covers them).
                if (bm0 != bn0) {
                    const int gm0 = bm0 + wr + mt * 16 + r0;
                    const size_t tb = (size_t)gn * N + gm0;
                    const f32x4 at = *(const f32x4*)(aux + tb);
                    bf16x4 v;
#pragma unroll
                    for (int r = 0; r < 4; r++) v[r] = (bf16)((acc[mt][nt][r] + 1.0f) * at[r]);
                    *(bf16x4*)((bf16*)out + tb) = v;
                }
            }
        }
    }
}

extern "C" void kernel_launch(void* const* d_in, const int* in_sizes, int n_in,
                              void* d_out, int out_size, void* d_ws, size_t ws_size,
                              hipStream_t stream) {
    const float* H_v   = (const float*)d_in[0];
    const float* H_e   = (const float*)d_in[1];
    // d_in[2] = adj_e : UNUSED by the reference
    const float* adj_v = (const float*)d_in[3];
    const float* T     = (const float*)d_in[4];
    const float* W     = (const float*)d_in[5];
    const float* p     = (const float*)d_in[6];
    const float* bias  = (const float*)d_in[7];
    float* out = (float*)d_out;

    // workspace layout (~176.7 MB)
    char* ws = (char*)d_ws;
    float* es  = (float*)(ws);                        // 32 KB
    bf16*  Ts  = (bf16*)(ws + 32768);                 // 64 MB
    bf16*  Tb  = (bf16*)(ws + 32768 + 67108864ull);   // 64 MB
    bf16*  A2  = (bf16*)(ws + 32768 + 134217728ull);  // 32 MB
    bf16*  Hvb = (bf16*)(ws + 32768 + 167772160ull);  // 4 MB
    bf16*  Wt  = (bf16*)(ws + 32768 + 171966464ull);  // 512 KB
    bf16*  HwT = (bf16*)(ws + 32768 + 172490752ull);  // 4 MB
    // split-K f32 partials (4 x 8 MB = 32 MB) alias Ts: Ts is dead once
    // gemm_bt<1> completes, and gemm_bt<3> is stream-ordered after it.
    float* part = (float*)(ws + 32768);

    // 1. e_scale = H_e @ p^T
    escale_k<<<N_EDGES / 4, 256, 0, stream>>>(H_e, p, es);
    // 2. bf16 conversions
    conv_T<<<(int)(((size_t)N_NODES * N_EDGES / 4) / 256), 256, 0, stream>>>(T, es, Ts, Tb);
    conv_bf16<<<(N_NODES * IN_V / 4) / 256, 256, 0, stream>>>(H_v, Hvb);
    transW<<<(IN_V * OUT_V) / 256, 256, 0, stream>>>(W, Wt);
    // second tuple output: H_e passthrough (independent; issue early)
    hipMemcpyAsync(out + (size_t)N_NODES * OUT_V, H_e,
                   (size_t)N_EDGES * IN_E * sizeof(float),
                   hipMemcpyDeviceToDevice, stream);
    // 3. HwT[j][i] = (H_v @ W)[i][j] = sum_k Wt[j,k]*Hvb[i,k]   (512 x 4096)
    gemm_bt<0><<<dim3(IN_V / 128, N_NODES / 128), 256, 0, stream>>>(
        Wt, Hvb, nullptr, HwT, IN_V, N_NODES, IN_V, IN_V);
    // 4. A2 = (M1 + 1) * adj_v, diag -> 2*adj_v  (4096 x 4096, K=8192)
    //    M1 symmetric -> triangular grid: 32*33/2 = 528 blocks, mirror writes.
    gemm_bt<1><<<dim3((32 * 33) / 2, 1, 1), 256, 0, stream>>>(
        Ts, Tb, adj_v, A2, N_NODES, N_NODES, N_EDGES, N_EDGES);
    // 5. partial[z] = A2 @ Hw slice  (4096 x 512, K=4096, split-K=4, f32 stores)
    gemm_bt<3><<<dim3(N_NODES / 128, OUT_V / 128, 4), 256, 0, stream>>>(
        A2, HwT, nullptr, part, N_NODES, OUT_V, N_NODES, N_NODES / 4);
    // 6. out = bias + 0.5 * sum_z partial[z]
    finalize_k<<<(N_NODES * OUT_V / 4) / 256, 256, 0, stream>>>(part, bias, out);
}